// Round 5
// baseline (255.456 us; speedup 1.0000x reference)
//
#include <hip/hip_runtime.h>

#define NZ 1e-5f
#define TC 16   // timesteps per staged LDS tile

__device__ __forceinline__ float fast_exp2(float x) {
#if __has_builtin(__builtin_amdgcn_exp2f)
    return __builtin_amdgcn_exp2f(x);   // v_exp_f32
#else
    return exp2f(x);
#endif
}

__device__ __forceinline__ float fast_log2(float x) {
#if __has_builtin(__builtin_amdgcn_logf)
    return __builtin_amdgcn_logf(x);    // v_log_f32 (base-2)
#else
    return log2f(x);
#endif
}

// Async global->LDS, 16B/lane. LDS dest is wave-uniform base + lane*16;
// global source address is per-lane.
__device__ __forceinline__ void gload_lds16(const float* src, float* dst_lds) {
    __builtin_amdgcn_global_load_lds(
        (const __attribute__((address_space(1))) void*)src,
        (__attribute__((address_space(3))) void*)dst_lds,
        16, 0, 0);
}

// R0-R4 post-mortem: ~720 cy/step invariant across register-ring, async-LDS,
// skewed-pipeline, and producer/consumer-wave structures; memory, issue, and
// wave-TLP all exonerated. Surviving model: the serial chain through 4
// dependent transcendentals/step (sw: log2->exp2, then ef: log2->exp2, ordered
// through SM). R5: relocate the sw pair (and C*SLZ) into the PREVIOUS step's
// tail -- sw(t) needs only end-of-step-(t-1) SM, which is ready before the
// routing block. Routing (~14 ops) + next step's snow (~21 ops) cover its
// latency; on-chain trans drops 4 -> 2. All expressions keep their exact
// form: bit-identical to the passing kernels.
__global__ __launch_bounds__(64, 1) void hbv_kernel(
    const float* __restrict__ precip,
    const float* __restrict__ temp,
    const float* __restrict__ pet,
    const float* __restrict__ phy,
    float* __restrict__ out,
    int G, int T)
{
    // [buf][array][t_sub][g_sub] : 2*3*16*64*4 = 24576 B
    __shared__ float lds[2][3][TC][64];

    const int lane = threadIdx.x;            // 0..63
    const int g0   = blockIdx.x * 64;
    const int g    = g0 + lane;
    const bool valid = (g < G);
    const int gp   = valid ? g : (G - 1);    // clamped (no early return: all
                                             // lanes must participate in staging)

    // Parameter bounds (compile-time constants, folded)
    const float lo[14] = {1.0f, 50.0f, 0.05f, 0.01f, 0.001f, 0.2f, 0.0f,
                          0.0f, -2.5f, 0.5f, 0.0f, 0.0f, 0.3f, 0.0f};
    const float hi[14] = {6.0f, 1000.0f, 0.9f, 0.5f, 0.2f, 1.0f, 10.0f,
                          100.0f, 2.5f, 10.0f, 0.1f, 0.2f, 5.0f, 1.0f};
    float p[14];
#pragma unroll
    for (int i = 0; i < 14; ++i)
        p[i] = lo[i] + phy[gp * 14 + i] * (hi[i] - lo[i]);

    const float BETA = p[0], FC = p[1], K0 = p[2], K1 = p[3], K2 = p[4];
    const float LP = p[5], PERCp = p[6], UZL = p[7], TT = p[8], CFMAX = p[9];
    const float CFR = p[10], CWH = p[11], BETAET = p[12], C = p[13];
    const float invFC   = 1.0f / FC;
    const float invLPFC = 1.0f / (LP * FC);
    const float CFRX    = CFR * CFMAX;
    (void)LP; (void)CFR;

    // State (registers for the whole scan)
    float SP = NZ, MW = NZ, SM = NZ, SUZ = NZ, SLZ = NZ;

    // Carried values, relocated from the step head to the previous step's
    // tail. Values are EXACTLY what the in-step computation would produce:
    // sw(t) = min(exp2(BETA*log2(SM_end(t-1)*invFC)), 1);  CSLZ = C*SLZ_end.
    float swc  = fminf(fast_exp2(BETA * fast_log2(SM * invFC)), 1.0f);
    float CSLZ = C * SLZ;

    // One HBV step with the carried-sw structure. Expression forms are
    // verbatim from the verified kernel (bit-identical results).
    auto hbv_step = [&](float pr, float tm, float pe) -> float {
        // --- snow subsystem (off the SM critical chain) ---
        const float RAIN = (tm >= TT) ? pr : 0.0f;
        const float SNOW = pr - RAIN;
        SP += SNOW;
        float melt = fminf(fmaxf(CFMAX * (tm - TT), 0.0f), SP);
        MW += melt;
        SP -= melt;
        float refr = fminf(fmaxf(CFRX * (TT - tm), 0.0f), MW);
        SP += refr;
        MW -= refr;
        float tosoil = fmaxf(MW - CWH * SP, 0.0f);
        MW -= tosoil;
        float rt = RAIN + tosoil;
        // --- soil: uses carried swc (== sw computed from current SM) ---
        float recharge = rt * swc;
        SM += rt - recharge;
        float excess = fmaxf(SM - FC, 0.0f);
        SM -= excess;
        float ef = fminf(fast_exp2(BETAET * fast_log2(SM * invLPFC)), 1.0f);
        float ETact = fminf(SM, pe * ef);
        SM = fmaxf(SM - ETact, NZ);
        float cap = fminf(SLZ, CSLZ * (1.0f - fminf(SM * invFC, 1.0f)));
        SM = fmaxf(SM + cap, NZ);
        SLZ = fmaxf(SLZ - cap, NZ);
        // --- next step's sw: START the log2 here; the routing block below
        // is independent of SM and covers its latency; the exp2 result is
        // first needed only after next step's snow chain. ---
        const float Lnext = fast_log2(SM * invFC);
        // --- routing (SUZ/SLZ only; never touches SM) ---
        SUZ += recharge + excess;
        float PERC = fminf(SUZ, PERCp);
        SUZ -= PERC;
        float Q0 = K0 * fmaxf(SUZ - UZL, 0.0f);
        SUZ -= Q0;
        float Q1 = K1 * SUZ;
        SUZ -= Q1;
        SLZ = fmaxf(SLZ + PERC, 0.0f);
        float Q2 = K2 * SLZ;
        SLZ -= Q2;
        // carried values for next step (exact relocations)
        CSLZ = C * SLZ;
        swc  = fminf(fast_exp2(BETA * Lnext), 1.0f);
        return Q0 + Q1 + Q2;
    };

    if ((G & 3) == 0) {
        // ---- fast path: async LDS staging (needs 16B-aligned rows: G%4==0) ----
        const int rsub = lane >> 4;          // which row of the 4-row quad
        const int csub = (lane & 15) << 2;   // float col within the 64-basin row
        int gcol = g0 + csub;
        if (gcol > G - 4) gcol = G - 4;      // clamp (only ever hits invalid basins)

        const int nt = (T + TC - 1) / TC;

        // One tile = 16 rows x 64 basins x 3 arrays. Each width-16 load covers
        // 4 rows (64 lanes x 16B = 1KiB): 4 instrs/array, 12 per tile.
        auto issue_tile = [&](int k, int b) {
            const int t0 = k * TC;
#pragma unroll
            for (int q = 0; q < TC / 4; ++q) {
                int t = t0 + 4 * q + rsub;
                if (t > T - 1) t = T - 1;    // tail clamp: duplicate rows, never consumed
                const size_t off = (size_t)t * G + gcol;
                gload_lds16(precip + off, &lds[b][0][4 * q][0]);
                gload_lds16(temp   + off, &lds[b][1][4 * q][0]);
                gload_lds16(pet    + off, &lds[b][2][4 * q][0]);
            }
        };

        issue_tile(0, 0);
        asm volatile("s_waitcnt vmcnt(0)" ::: "memory");
        __builtin_amdgcn_sched_barrier(0);

        for (int k = 0; k < nt; ++k) {
            const int b = k & 1;
            if (k + 1 < nt) {
                issue_tile(k + 1, b ^ 1);            // 12 loads in flight across
                __builtin_amdgcn_sched_barrier(0);   // the whole tile's compute
            }
            const int t0 = k * TC;
#pragma unroll
            for (int j = 0; j < TC; ++j) {
                const int t = t0 + j;
                const float pr = lds[b][0][j][lane]; // stride-1: 2-way alias, free
                const float tm = lds[b][1][j][lane];
                const float pe = lds[b][2][j][lane];
                const float q = hbv_step(pr, tm, pe);
                if (valid && t < T)
                    out[(size_t)t * G + g] = q;
            }
            if (k + 1 < nt) {
                // Counted wait: queue = [12 loads][16 stores]. vmcnt(12)
                // retires the 12 next-tile loads (issued a full tile of
                // compute ago -> ~zero stall) + 4 stores; 12 stores stay
                // outstanding.
                asm volatile("s_waitcnt vmcnt(12)" ::: "memory");
                __builtin_amdgcn_sched_barrier(0);
            }
        }
    } else {
        // ---- generic fallback (not taken for the bench shape) ----
        for (int t = 0; t < T; ++t) {
            const size_t idx = (size_t)t * G + gp;
            const float q = hbv_step(precip[idx], temp[idx], pet[idx]);
            if (valid) out[idx] = q;
        }
    }
}

extern "C" void kernel_launch(void* const* d_in, const int* in_sizes, int n_in,
                              void* d_out, int out_size, void* d_ws, size_t ws_size,
                              hipStream_t stream) {
    const float* precip = (const float*)d_in[0];
    const float* temp   = (const float*)d_in[1];
    const float* pet    = (const float*)d_in[2];
    const float* phy    = (const float*)d_in[3];
    float* out = (float*)d_out;

    const int G = in_sizes[3] / 14;   // 50000
    const int T = in_sizes[0] / G;    // 365

    dim3 block(64);
    dim3 grid((G + 63) / 64);         // 782 blocks, 1 wave each
    hbv_kernel<<<grid, block, 0, stream>>>(precip, temp, pet, phy, out, G, T);
}

// Round 6
// 251.153 us; speedup vs baseline: 1.0171x; 1.0171x over previous
//
#include <hip/hip_runtime.h>

#define NZ 1e-5f
#define TC 12   // timesteps per register-buffered tile (36 loads + 12 stores <= 63 vmcnt)

__device__ __forceinline__ float fast_exp2(float x) {
#if __has_builtin(__builtin_amdgcn_exp2f)
    return __builtin_amdgcn_exp2f(x);   // v_exp_f32
#else
    return exp2f(x);
#endif
}

__device__ __forceinline__ float fast_log2(float x) {
#if __has_builtin(__builtin_amdgcn_logf)
    return __builtin_amdgcn_logf(x);    // v_log_f32 (base-2)
#else
    return log2f(x);
#endif
}

// R0-R5 post-mortem: wall = 365 * recurrence-cycle latency. The SM cycle
// (swc-pair -> recharge -> ef-pair -> ETact -> cap) contains 4 transcendentals
// + ~25 dependent ALU ops regardless of issue order; every reorder/wave-split
// left it intact -> all versions ~110us. R6 attacks the only real levers:
//  (1) shorten the cycle with EXACT identities:
//      SM -= max(SM-FC,0)            == min(SM,FC)          (3 ops -> 1)
//      SM = max(SM-min(SM,x),NZ)     == max(SM-x,NZ)        (bit-exact, 4 -> 3)
//  (2) remove ALL per-step memory from the loop: pure-register double-buffered
//      forcing tiles (no LDS). 36 independent global_load_dword are issued as
//      a batch and pinned above the compute by sched_barrier(0) -- the
//      register allocator cannot collapse this pipeline (R0's failure mode).
__global__ __launch_bounds__(64, 1) void hbv_kernel(
    const float* __restrict__ precip,
    const float* __restrict__ temp,
    const float* __restrict__ pet,
    const float* __restrict__ phy,
    float* __restrict__ out,
    int G, int T)
{
    const int lane = threadIdx.x;            // 0..63
    const int g0   = blockIdx.x * 64;
    const int g    = g0 + lane;
    const bool valid = (g < G);
    const int gp   = valid ? g : (G - 1);    // clamped index for loads

    // Parameter bounds (compile-time constants, folded)
    const float lo[14] = {1.0f, 50.0f, 0.05f, 0.01f, 0.001f, 0.2f, 0.0f,
                          0.0f, -2.5f, 0.5f, 0.0f, 0.0f, 0.3f, 0.0f};
    const float hi[14] = {6.0f, 1000.0f, 0.9f, 0.5f, 0.2f, 1.0f, 10.0f,
                          100.0f, 2.5f, 10.0f, 0.1f, 0.2f, 5.0f, 1.0f};
    float p[14];
#pragma unroll
    for (int i = 0; i < 14; ++i)
        p[i] = lo[i] + phy[gp * 14 + i] * (hi[i] - lo[i]);

    const float BETA = p[0], FC = p[1], K0 = p[2], K1 = p[3], K2 = p[4];
    const float LP = p[5], PERCp = p[6], UZL = p[7], TT = p[8], CFMAX = p[9];
    const float CFR = p[10], CWH = p[11], BETAET = p[12], C = p[13];
    const float invFC   = 1.0f / FC;
    const float invLPFC = 1.0f / (LP * FC);
    const float CFRX    = CFR * CFMAX;
    (void)LP; (void)CFR;

    // State
    float SP = NZ, MW = NZ, SM = NZ, SUZ = NZ, SLZ = NZ;
    // Carried values (exact relocations, verified in R5):
    float swc  = fminf(fast_exp2(BETA * fast_log2(SM * invFC)), 1.0f);
    float CSLZ = C * SLZ;

    // --- One HBV step. Exact-identity fusions vs the verified kernel:
    //  * excess/clamp:  excess = max(s_pre-FC,0) kept verbatim (feeds SUZ);
    //                   SM = min(s_pre,FC) replaces s_pre-excess (==, +/-1ulp
    //                   only when s_pre>FC, where ref's subtract-back rounds).
    //  * ETact:         SM = max(SM - pe*ef, NZ) is BIT-exact vs
    //                   ETact=min(SM,pe*ef); SM=max(SM-ETact,NZ).
    auto hbv_step = [&](float pr, float tm, float pe) -> float {
        // snow subsystem (feeds the cycle only through rt)
        const float RAIN = (tm >= TT) ? pr : 0.0f;
        const float SNOW = pr - RAIN;
        SP += SNOW;
        float melt = fminf(fmaxf(CFMAX * (tm - TT), 0.0f), SP);
        MW += melt;
        SP -= melt;
        float refr = fminf(fmaxf(CFRX * (TT - tm), 0.0f), MW);
        SP += refr;
        MW -= refr;
        float tosoil = fmaxf(MW - CWH * SP, 0.0f);
        MW -= tosoil;
        const float rt = RAIN + tosoil;
        // soil (the recurrence cycle)
        const float recharge = rt * swc;
        const float s_pre = SM + rt - recharge;
        const float excess = fmaxf(s_pre - FC, 0.0f);   // off-cycle (-> SUZ)
        SM = fminf(s_pre, FC);                          // fused clamp
        const float ef = fminf(fast_exp2(BETAET * fast_log2(SM * invLPFC)), 1.0f);
        SM = fmaxf(SM - pe * ef, NZ);                   // fused ETact (bit-exact)
        const float cap = fminf(SLZ, CSLZ * (1.0f - fminf(SM * invFC, 1.0f)));
        SM = fmaxf(SM + cap, NZ);
        SLZ = fmaxf(SLZ - cap, NZ);
        const float Lnext = fast_log2(SM * invFC);      // next swc's log2
        // routing (off the SM cycle)
        SUZ += recharge + excess;
        const float PERC = fminf(SUZ, PERCp);
        SUZ -= PERC;
        const float Q0 = K0 * fmaxf(SUZ - UZL, 0.0f);
        SUZ -= Q0;
        const float Q1 = K1 * SUZ;
        SUZ -= Q1;
        SLZ = fmaxf(SLZ + PERC, 0.0f);
        const float Q2 = K2 * SLZ;
        SLZ -= Q2;
        CSLZ = C * SLZ;
        swc  = fminf(fast_exp2(BETA * Lnext), 1.0f);
        return Q0 + Q1 + Q2;
    };

    const int nfull = T / TC;
    const int tail  = T - nfull * TC;

    if (nfull >= 2 && (nfull & 1) == 0) {
        // ---- fast path: register double-buffered tiles ----
        float prA[TC], tmA[TC], peA[TC], prB[TC], tmB[TC], peB[TC];

        // Issue TC*3 independent dword loads (clamped t for the tail tile).
        auto load_tile = [&](int k, float (&P)[TC], float (&M)[TC], float (&E)[TC]) {
#pragma unroll
            for (int j = 0; j < TC; ++j) {
                int t = k * TC + j;
                if (t > T - 1) t = T - 1;
                const size_t off = (size_t)t * G + gp;
                P[j] = precip[off];
                M[j] = temp[off];
                E[j] = pet[off];
            }
        };

        auto compute_tile = [&](const float (&P)[TC], const float (&M)[TC],
                                const float (&E)[TC], int t0, bool full) {
#pragma unroll
            for (int j = 0; j < TC; ++j) {
                const float q = hbv_step(P[j], M[j], E[j]);
                // beyond-T steps (tail tile) compute harmless clamped garbage
                // state; nothing after the tail consumes state.
                if ((full || (t0 + j) < T) && valid)
                    out[(size_t)(t0 + j) * G + g] = q;
            }
        };

        load_tile(0, prA, tmA, peA);
        __builtin_amdgcn_sched_barrier(0);   // pin loads above all later compute

        for (int k = 0; k < nfull; k += 2) {
            load_tile(k + 1, prB, tmB, peB);
            __builtin_amdgcn_sched_barrier(0);
            compute_tile(prA, tmA, peA, k * TC, true);

            load_tile(k + 2, prA, tmA, peA);     // k+2==nfull -> tail tile (clamped)
            __builtin_amdgcn_sched_barrier(0);
            compute_tile(prB, tmB, peB, (k + 1) * TC, true);
        }
        if (tail)
            compute_tile(prA, tmA, peA, nfull * TC, false);
    } else {
        // ---- generic fallback (not taken for the bench shape) ----
        for (int t = 0; t < T; ++t) {
            const size_t idx = (size_t)t * G + gp;
            const float q = hbv_step(precip[idx], temp[idx], pet[idx]);
            if (valid) out[idx] = q;
        }
    }
}

extern "C" void kernel_launch(void* const* d_in, const int* in_sizes, int n_in,
                              void* d_out, int out_size, void* d_ws, size_t ws_size,
                              hipStream_t stream) {
    const float* precip = (const float*)d_in[0];
    const float* temp   = (const float*)d_in[1];
    const float* pet    = (const float*)d_in[2];
    const float* phy    = (const float*)d_in[3];
    float* out = (float*)d_out;

    const int G = in_sizes[3] / 14;   // 50000
    const int T = in_sizes[0] / G;    // 365

    dim3 block(64);
    dim3 grid((G + 63) / 64);         // 782 blocks, 1 wave each
    hbv_kernel<<<grid, block, 0, stream>>>(precip, temp, pet, phy, out, G, T);
}